// Round 6
// baseline (32.998 us; speedup 1.0000x reference)
//
#include <hip/hip_runtime.h>
#include <stdint.h>

#define NANCH   8192
#define NCLS    80
#define IMW     1024
#define IMH     1024
#define MAXDET  100
#define SCORE_TH 0.05f
#define TAU      0.9995f      // P(max80 > tau) ~= 0.0392 -> ~321 survivors/batch of 8192
#define CAP      1536         // 69 sigma above mean survivor count

// key layout: [63:32] monotonic(score) | [31:16] ~anchor_idx (stable tie-break) | [15:0] class
// meta layout: 4 x int16 box coords (x1,y1,x2,y2)
__device__ __forceinline__ float key_score(uint64_t key) {
    uint32_t m = (uint32_t)(key >> 32);
    uint32_t bits = (m & 0x80000000u) ? (m & 0x7FFFFFFFu) : ~m;
    return __uint_as_float(bits);
}

// ---------------- Kernel 1: decode + threshold compaction (no sort) ----------------
__global__ __launch_bounds__(64)
void decode_kernel(const float* __restrict__ cls_heads,
                   const float* __restrict__ reg_heads,
                   const float* __restrict__ anchors,
                   int* __restrict__ cnt,
                   uint64_t* __restrict__ wk,
                   uint64_t* __restrict__ wm,
                   ulonglong2* __restrict__ surv) {
    const int lane = threadIdx.x;
    const int b    = blockIdx.y;
    const int n    = blockIdx.x * 64 + lane;
    const int row  = b * NANCH + n;

    const float4* cp = reinterpret_cast<const float4*>(cls_heads + (size_t)row * NCLS);
    float best = -1e30f; int bestj = 0;
#pragma unroll
    for (int k = 0; k < NCLS / 4; ++k) {
        float4 v = cp[k];
        if (v.x > best) { best = v.x; bestj = 4 * k + 0; }
        if (v.y > best) { best = v.y; bestj = 4 * k + 1; }
        if (v.z > best) { best = v.z; bestj = 4 * k + 2; }
        if (v.w > best) { best = v.w; bestj = 4 * k + 3; }
    }

    float4 r = reinterpret_cast<const float4*>(reg_heads)[row];
    float4 a = reinterpret_cast<const float4*>(anchors)[row];

    // decode — _rn intrinsics block fma contraction (trunc boundaries ulp-sensitive)
    float awx = __fsub_rn(a.z, a.x);
    float awy = __fsub_rn(a.w, a.y);
    float acx = __fadd_rn(a.x, __fmul_rn(0.5f, awx));
    float acy = __fadd_rn(a.y, __fmul_rn(0.5f, awy));
    float rx = __fmul_rn(r.x, 0.1f);
    float ry = __fmul_rn(r.y, 0.1f);
    float rw = __fmul_rn(r.z, 0.2f);
    float rh = __fmul_rn(r.w, 0.2f);
    float pwx = __fmul_rn(expf(rw), awx);
    float pwy = __fmul_rn(expf(rh), awy);
    float pcx = __fadd_rn(__fmul_rn(rx, awx), acx);
    float pcy = __fadd_rn(__fmul_rn(ry, awy), acy);

    int x1 = (int)__fsub_rn(pcx, __fmul_rn(0.5f, pwx));
    int y1 = (int)__fsub_rn(pcy, __fmul_rn(0.5f, pwy));
    int x2 = (int)__fadd_rn(pcx, __fmul_rn(0.5f, pwx));
    int y2 = (int)__fadd_rn(pcy, __fmul_rn(0.5f, pwy));
    x1 = max(x1, 0);
    y1 = max(y1, 0);
    x2 = min(x2, IMW - 1);
    y2 = min(y2, IMH - 1);

    uint32_t u = __float_as_uint(best);
    uint32_t mono = (u & 0x80000000u) ? ~u : (u | 0x80000000u);
    uint64_t key = ((uint64_t)mono << 32)
                 | ((uint64_t)((~(uint32_t)n) & 0xFFFFu) << 16)
                 | (uint64_t)(uint32_t)bestj;
    uint64_t meta = (uint64_t)(uint16_t)x1
                  | ((uint64_t)(uint16_t)y1 << 16)
                  | ((uint64_t)(uint16_t)x2 << 32)
                  | ((uint64_t)(uint16_t)y2 << 48);

    wk[row] = key;
    wm[row] = meta;

    if (best > TAU) {
        int p = atomicAdd(&cnt[b], 1);
        if (p < CAP) surv[(size_t)b * CAP + p] = make_ulonglong2(key, meta);
    }
}

// ---------------- fallback helper (cold path, exact) ----------------
struct Kept {
    float x1[2], y1[2], x2[2], y2[2], ar[2];
    int   cl[2];
};

__device__ __forceinline__ void nms_try_keep(uint64_t key, uint64_t meta, float s,
                                             int lane, int& nk, Kept& K,
                                             float* __restrict__ out, int b) {
    int cls = (int)(key & 0xFFFFu);
    float cx1 = (float)(short)(meta & 0xFFFFu);
    float cy1 = (float)(short)((meta >> 16) & 0xFFFFu);
    float cx2 = (float)(short)((meta >> 32) & 0xFFFFu);
    float cy2 = (float)(short)((meta >> 48) & 0xFFFFu);
    float ca = fmaxf(cx2 - cx1, 0.f) * fmaxf(cy2 - cy1, 0.f);

    bool supp = false;
#pragma unroll
    for (int r = 0; r < 2; ++r) {
        int slot = lane + 64 * r;
        if (slot < nk && K.cl[r] == cls) {
            float ix1 = fmaxf(K.x1[r], cx1), iy1 = fmaxf(K.y1[r], cy1);
            float ix2 = fminf(K.x2[r], cx2), iy2 = fminf(K.y2[r], cy2);
            float inter = fmaxf(ix2 - ix1, 0.f) * fmaxf(iy2 - iy1, 0.f);
            if (3.f * inter > K.ar[r] + ca) supp = true;   // exact iou>0.5 (ints exact in f32)
        }
    }
    if (__ballot(supp) != 0ULL) return;

    int rr = nk >> 6, l = nk & 63;
    if (lane == l) {
        if (rr == 0) { K.x1[0]=cx1; K.y1[0]=cy1; K.x2[0]=cx2; K.y2[0]=cy2; K.ar[0]=ca; K.cl[0]=cls; }
        else         { K.x1[1]=cx1; K.y1[1]=cy1; K.x2[1]=cx2; K.y2[1]=cy2; K.ar[1]=ca; K.cl[1]=cls; }
    }
    if (lane == 0) {
        out[b * MAXDET + nk] = s;
        out[2 * MAXDET + b * MAXDET + nk] = (float)cls;
        float* ob = out + 4 * MAXDET + (size_t)(b * MAXDET + nk) * 4;
        ob[0] = cx1; ob[1] = cy1; ob[2] = cx2; ob[3] = cy2;
    }
    ++nk;
}

// ---------------- Kernel 2: rank-order sort of survivors + batched NMS ----------------
__global__ __launch_bounds__(1024)
void sort_nms_kernel(const int* __restrict__ cnt,
                     const uint64_t* __restrict__ wk,
                     const uint64_t* __restrict__ wm,
                     const ulonglong2* __restrict__ surv,
                     float* __restrict__ out) {
    __shared__ __align__(16) ulonglong2 sv[CAP];     // unordered survivors
    __shared__ __align__(16) ulonglong2 sq[CAP];     // rank-sorted survivors
    __shared__ float4 kept_box[MAXDET];
    __shared__ float  kept_area[MAXDET];
    __shared__ int    kept_cls[MAXDET];
    __shared__ float4 sbox[64];
    __shared__ float  sarea[64];
    __shared__ int    scls[64];
    __shared__ uint64_t fbmap[NANCH / 64];

    const int b = blockIdx.x;
    const int tid = threadIdx.x;
    const int lane = tid & 63;

    int c = cnt[b];
    bool overflow = (c > CAP) || (c < 0);
    if (overflow) c = 0;                 // skip main path; fallback handles it
    const int cpad = (c + 63) & ~63;

    // stage survivors to LDS
    for (int i = tid; i < c; i += 1024) sv[i] = surv[(size_t)b * CAP + i];
    __syncthreads();

    // rank-order sort: rank_i = #{j: key_j > key_i}; keys unique -> exact descending order.
    // pure throughput (LDS broadcast reads), no dependent cross-lane ops.
    for (int i = tid; i < c; i += 1024) {
        ulonglong2 v = sv[i];
        int r = 0;
        for (int j = 0; j < c; ++j) r += (sv[j].x > v.x) ? 1 : 0;
        sq[r] = v;
    }
    for (int i = c + tid; i < cpad; i += 1024) sq[i] = make_ulonglong2(0ULL, 0ULL);
    __syncthreads();

    if (tid >= 64) return;

    // ---- wave 0: batched greedy NMS over sorted survivors ----
    int nk = 0;
    bool need_fb = overflow;
    bool done = false;

    for (int p0 = 0; p0 < cpad && !done; p0 += 64) {
        ulonglong2 kv = sq[p0 + lane];
        uint64_t key = kv.x, meta = kv.y;
        float s = key_score(key);                     // key==0 pad -> NaN -> invalid
        bool sval = (s > SCORE_TH);
        int cls_c = sval ? (int)(key & 0xFFFFu) : -1;
        float cx1 = (float)(short)(meta & 0xFFFFu);
        float cy1 = (float)(short)((meta >> 16) & 0xFFFFu);
        float cx2 = (float)(short)((meta >> 32) & 0xFFFFu);
        float cy2 = (float)(short)((meta >> 48) & 0xFFFFu);
        float ca = fmaxf(cx2 - cx1, 0.f) * fmaxf(cy2 - cy1, 0.f);

        sbox[lane]  = make_float4(cx1, cy1, cx2, cy2);
        sarea[lane] = ca;
        scls[lane]  = sval ? (int)(key & 0xFFFFu) : 0x7FFF;
        __builtin_amdgcn_wave_barrier();

        // vs previously-kept set (LDS broadcast reads)
        bool supk = false;
        for (int j = 0; j < nk; ++j) {
            float4 kb = kept_box[j];
            float ix1 = fmaxf(kb.x, cx1), iy1 = fmaxf(kb.y, cy1);
            float ix2 = fminf(kb.z, cx2), iy2 = fminf(kb.w, cy2);
            float inter = fmaxf(ix2 - ix1, 0.f) * fmaxf(iy2 - iy1, 0.f);
            supk |= (kept_cls[j] == cls_c) & (3.f * inter > kept_area[j] + ca);
        }
        bool alive0 = sval && !supk;

        // intra-batch pairwise suppression mask
        uint64_t supBy = 0;
#pragma unroll 4
        for (int t = 0; t < 64; ++t) {
            float4 tb = sbox[t];
            float ta = sarea[t];
            int tcls = scls[t];
            float ix1 = fmaxf(tb.x, cx1), iy1 = fmaxf(tb.y, cy1);
            float ix2 = fminf(tb.z, cx2), iy2 = fminf(tb.w, cy2);
            float inter = fmaxf(ix2 - ix1, 0.f) * fmaxf(iy2 - iy1, 0.f);
            bool sup = (t < lane) && (tcls == cls_c) && (3.f * inter > ta + ca);
            supBy |= ((uint64_t)sup) << t;
        }

        uint64_t aliveCand = __ballot(alive0);
        uint64_t aliveMask;
        if (__ballot(supBy != 0ULL) == 0ULL) {
            aliveMask = aliveCand;          // fast path: no intra-batch suppression
        } else {
            uint64_t killed = 0;
            for (int t = 0; t < 64; ++t) {
                uint64_t kill_t = __ballot((supBy >> t) & 1ULL);
                bool talive = ((aliveCand >> t) & 1ULL) && !((killed >> t) & 1ULL);
                if (talive) killed |= kill_t;
            }
            aliveMask = aliveCand & ~killed;
        }

        int myrank = __popcll(aliveMask & ((1ULL << lane) - 1ULL));
        bool keepme = ((aliveMask >> lane) & 1ULL) && (nk + myrank < MAXDET);
        if (keepme) {
            int slot = nk + myrank;
            kept_box[slot]  = make_float4(cx1, cy1, cx2, cy2);
            kept_area[slot] = ca;
            kept_cls[slot]  = cls_c;
            out[b * MAXDET + slot] = s;
            out[2 * MAXDET + b * MAXDET + slot] = (float)cls_c;
            float* ob = out + 4 * MAXDET + (size_t)(b * MAXDET + slot) * 4;
            ob[0] = cx1; ob[1] = cy1; ob[2] = cx2; ob[3] = cy2;
        }
        int navail = __popcll(aliveMask);
        int room = MAXDET - nk;
        nk += (navail < room) ? navail : room;

        uint64_t invalid = __ballot(!sval);
        if (nk >= MAXDET) done = true;
        else if (invalid) { need_fb = true; done = true; }   // survivors exhausted short
    }
    if (!done && nk < MAXDET) need_fb = true;

    // ---- cold exact fallback: repeated max-extraction over all 8192 keys ----
    if (need_fb) {
        const uint64_t* wkb = wk + (size_t)b * NANCH;
        const uint64_t* wmb = wm + (size_t)b * NANCH;
        for (int i = lane; i < NANCH / 64; i += 64) fbmap[i] = 0ULL;
        __builtin_amdgcn_wave_barrier();

        nk = 0;
        Kept K;
        K.cl[0] = K.cl[1] = -1;
        K.x1[0]=K.y1[0]=K.x2[0]=K.y2[0]=K.ar[0]=0.f;
        K.x1[1]=K.y1[1]=K.x2[1]=K.y2[1]=K.ar[1]=0.f;

        for (int iter = 0; iter < NANCH; ++iter) {
            uint64_t mybest = 0; int myq = -1;
            for (int q = lane; q < NANCH; q += 64) {
                bool cons = (fbmap[q >> 6] >> (q & 63)) & 1ULL;
                uint64_t kk = wkb[q];
                if (!cons && kk > mybest) { mybest = kk; myq = q; }
            }
            uint64_t best = mybest;
#pragma unroll
            for (int j = 32; j; j >>= 1) {
                uint64_t o = __shfl_xor(best, j);
                if (o > best) best = o;
            }
            if (best == 0ULL) break;
            float s = key_score(best);
            if (!(s > SCORE_TH)) break;
            uint64_t msk = __ballot(mybest == best);
            int wl = __ffsll((unsigned long long)msk) - 1;
            int q = __shfl(myq, wl);
            if (lane == wl) fbmap[q >> 6] |= (1ULL << (q & 63));
            uint64_t cm = wmb[q];                       // uniform address, broadcast load
            nms_try_keep(best, cm, s, lane, nk, K, out, b);
            if (nk == MAXDET) break;
            __builtin_amdgcn_wave_barrier();
        }
    }

    // pad remaining slots with -1
    for (int t = nk + lane; t < MAXDET; t += 64) {
        out[b * MAXDET + t] = -1.f;
        out[2 * MAXDET + b * MAXDET + t] = -1.f;
        float* ob = out + 4 * MAXDET + (size_t)(b * MAXDET + t) * 4;
        ob[0] = -1.f; ob[1] = -1.f; ob[2] = -1.f; ob[3] = -1.f;
    }
}

extern "C" void kernel_launch(void* const* d_in, const int* in_sizes, int n_in,
                              void* d_out, int out_size, void* d_ws, size_t ws_size,
                              hipStream_t stream) {
    (void)in_sizes; (void)n_in; (void)out_size; (void)ws_size;
    const float* cls_heads = (const float*)d_in[0];
    const float* reg_heads = (const float*)d_in[1];
    const float* anchors   = (const float*)d_in[2];
    float* out = (float*)d_out;

    // ws layout (aligned offsets)
    char* w = (char*)d_ws;
    int*        cnt  = (int*)w;                                  // 8 B
    uint64_t*   wk   = (uint64_t*)(w + 256);                     // 128 KiB
    uint64_t*   wm   = (uint64_t*)(w + 256 + 131072);            // 128 KiB
    ulonglong2* surv = (ulonglong2*)(w + 256 + 262144);          // 48 KiB

    hipMemsetAsync(cnt, 0, 2 * sizeof(int), stream);             // counters must be zero each replay
    decode_kernel<<<dim3(NANCH / 64, 2), 64, 0, stream>>>(cls_heads, reg_heads, anchors,
                                                          cnt, wk, wm, surv);
    sort_nms_kernel<<<dim3(2), 1024, 0, stream>>>(cnt, wk, wm, surv, out);
}

// Round 7
// 32.879 us; speedup vs baseline: 1.0036x; 1.0036x over previous
//
#include <hip/hip_runtime.h>
#include <stdint.h>

#define NANCH   8192
#define NCLS    80
#define NCHUNK  128            // 8192 / 64
#define IMW     1024
#define IMH     1024
#define MAXDET  100
#define SCORE_TH 0.05f
#define TAU      0.9995f      // P(max80 > tau) ~= 0.0392 -> ~321 survivors/batch
#define CAP      1536         // LDS staging capacity (69 sigma above mean)
#define NMS_THREADS 512

// key layout: [63:32] monotonic(score) | [31:16] ~anchor_idx (stable tie-break) | [15:0] class
// meta layout: 4 x int16 box coords (x1,y1,x2,y2)
__device__ __forceinline__ float key_score(uint64_t key) {
    uint32_t m = (uint32_t)(key >> 32);
    uint32_t bits = (m & 0x80000000u) ? (m & 0x7FFFFFFFu) : ~m;
    return __uint_as_float(bits);
}

// ---------------- Kernel 1: decode + per-chunk deterministic compaction ----------------
__global__ __launch_bounds__(256)
void decode_kernel(const float* __restrict__ cls_heads,
                   const float* __restrict__ reg_heads,
                   const float* __restrict__ anchors,
                   int* __restrict__ ccnt,
                   uint64_t* __restrict__ wk,
                   uint64_t* __restrict__ wm,
                   ulonglong2* __restrict__ surv) {
    const int tid  = threadIdx.x;
    const int lane = tid & 63;
    const int b    = blockIdx.y;
    const int n    = blockIdx.x * 256 + tid;
    const int chunk = n >> 6;
    const int row  = b * NANCH + n;

    const float4* cp = reinterpret_cast<const float4*>(cls_heads + (size_t)row * NCLS);
    float best = -1e30f; int bestj = 0;
#pragma unroll
    for (int k = 0; k < NCLS / 4; ++k) {
        float4 v = cp[k];
        if (v.x > best) { best = v.x; bestj = 4 * k + 0; }
        if (v.y > best) { best = v.y; bestj = 4 * k + 1; }
        if (v.z > best) { best = v.z; bestj = 4 * k + 2; }
        if (v.w > best) { best = v.w; bestj = 4 * k + 3; }
    }

    float4 r = reinterpret_cast<const float4*>(reg_heads)[row];
    float4 a = reinterpret_cast<const float4*>(anchors)[row];

    // decode — _rn intrinsics block fma contraction (trunc boundaries ulp-sensitive)
    float awx = __fsub_rn(a.z, a.x);
    float awy = __fsub_rn(a.w, a.y);
    float acx = __fadd_rn(a.x, __fmul_rn(0.5f, awx));
    float acy = __fadd_rn(a.y, __fmul_rn(0.5f, awy));
    float rx = __fmul_rn(r.x, 0.1f);
    float ry = __fmul_rn(r.y, 0.1f);
    float rw = __fmul_rn(r.z, 0.2f);
    float rh = __fmul_rn(r.w, 0.2f);
    float pwx = __fmul_rn(expf(rw), awx);
    float pwy = __fmul_rn(expf(rh), awy);
    float pcx = __fadd_rn(__fmul_rn(rx, awx), acx);
    float pcy = __fadd_rn(__fmul_rn(ry, awy), acy);

    int x1 = (int)__fsub_rn(pcx, __fmul_rn(0.5f, pwx));
    int y1 = (int)__fsub_rn(pcy, __fmul_rn(0.5f, pwy));
    int x2 = (int)__fadd_rn(pcx, __fmul_rn(0.5f, pwx));
    int y2 = (int)__fadd_rn(pcy, __fmul_rn(0.5f, pwy));
    x1 = max(x1, 0);
    y1 = max(y1, 0);
    x2 = min(x2, IMW - 1);
    y2 = min(y2, IMH - 1);

    uint32_t u = __float_as_uint(best);
    uint32_t mono = (u & 0x80000000u) ? ~u : (u | 0x80000000u);
    uint64_t key = ((uint64_t)mono << 32)
                 | ((uint64_t)((~(uint32_t)n) & 0xFFFFu) << 16)
                 | (uint64_t)(uint32_t)bestj;
    uint64_t meta = (uint64_t)(uint16_t)x1
                  | ((uint64_t)(uint16_t)y1 << 16)
                  | ((uint64_t)(uint16_t)x2 << 32)
                  | ((uint64_t)(uint16_t)y2 << 48);

    wk[row] = key;
    wm[row] = meta;

    // per-wave compaction into fixed per-chunk slots — no atomics, full overwrite each call
    bool svv = (best > TAU);
    uint64_t mask = __ballot(svv);
    int rank = __popcll(mask & ((1ULL << lane) - 1ULL));
    if (svv) surv[((size_t)b * NCHUNK + chunk) * 64 + rank] = make_ulonglong2(key, meta);
    if (lane == 0) ccnt[b * NCHUNK + chunk] = __popcll(mask);
}

// ---------------- fallback helper (cold path, exact) ----------------
struct Kept {
    float x1[2], y1[2], x2[2], y2[2], ar[2];
    int   cl[2];
};

__device__ __forceinline__ void nms_try_keep(uint64_t key, uint64_t meta, float s,
                                             int lane, int& nk, Kept& K,
                                             float* __restrict__ out, int b) {
    int cls = (int)(key & 0xFFFFu);
    float cx1 = (float)(short)(meta & 0xFFFFu);
    float cy1 = (float)(short)((meta >> 16) & 0xFFFFu);
    float cx2 = (float)(short)((meta >> 32) & 0xFFFFu);
    float cy2 = (float)(short)((meta >> 48) & 0xFFFFu);
    float ca = fmaxf(cx2 - cx1, 0.f) * fmaxf(cy2 - cy1, 0.f);

    bool supp = false;
#pragma unroll
    for (int r = 0; r < 2; ++r) {
        int slot = lane + 64 * r;
        if (slot < nk && K.cl[r] == cls) {
            float ix1 = fmaxf(K.x1[r], cx1), iy1 = fmaxf(K.y1[r], cy1);
            float ix2 = fminf(K.x2[r], cx2), iy2 = fminf(K.y2[r], cy2);
            float inter = fmaxf(ix2 - ix1, 0.f) * fmaxf(iy2 - iy1, 0.f);
            if (3.f * inter > K.ar[r] + ca) supp = true;   // exact iou>0.5 (ints exact in f32)
        }
    }
    if (__ballot(supp) != 0ULL) return;

    int rr = nk >> 6, l = nk & 63;
    if (lane == l) {
        if (rr == 0) { K.x1[0]=cx1; K.y1[0]=cy1; K.x2[0]=cx2; K.y2[0]=cy2; K.ar[0]=ca; K.cl[0]=cls; }
        else         { K.x1[1]=cx1; K.y1[1]=cy1; K.x2[1]=cx2; K.y2[1]=cy2; K.ar[1]=ca; K.cl[1]=cls; }
    }
    if (lane == 0) {
        out[b * MAXDET + nk] = s;
        out[2 * MAXDET + b * MAXDET + nk] = (float)cls;
        float* ob = out + 4 * MAXDET + (size_t)(b * MAXDET + nk) * 4;
        ob[0] = cx1; ob[1] = cy1; ob[2] = cx2; ob[3] = cy2;
    }
    ++nk;
}

// ---------------- Kernel 2: prefix-gather + rank sort + batched NMS ----------------
__global__ __launch_bounds__(NMS_THREADS)
void sort_nms_kernel(const int* __restrict__ ccnt,
                     const uint64_t* __restrict__ wk,
                     const uint64_t* __restrict__ wm,
                     const ulonglong2* __restrict__ surv,
                     float* __restrict__ out) {
    __shared__ __align__(16) ulonglong2 sv_[CAP];    // gathered survivors (unordered)
    __shared__ __align__(16) ulonglong2 sq[CAP];     // rank-sorted survivors
    __shared__ int soff[NCHUNK];
    __shared__ int scnt[NCHUNK];
    __shared__ int stotal;
    __shared__ float4 kept_box[MAXDET];
    __shared__ float  kept_area[MAXDET];
    __shared__ int    kept_cls[MAXDET];
    __shared__ float4 sbox[64];
    __shared__ float  sarea[64];
    __shared__ int    scls[64];
    __shared__ uint64_t fbmap[NANCH / 64];

    const int b = blockIdx.x;
    const int tid = threadIdx.x;
    const int lane = tid & 63;

    // ---- wave 0: prefix-sum of the 128 per-chunk counts ----
    if (tid < 64) {
        int a0 = ccnt[b * NCHUNK + 2 * tid];
        int a1 = ccnt[b * NCHUNK + 2 * tid + 1];
        int s = a0 + a1;
#pragma unroll
        for (int j = 1; j < 64; j <<= 1) {
            int o = __shfl_up(s, j);
            if (lane >= j) s += o;
        }
        int excl = s - (a0 + a1);
        soff[2 * tid] = excl;
        soff[2 * tid + 1] = excl + a0;
        scnt[2 * tid] = a0;
        scnt[2 * tid + 1] = a1;
        if (tid == 63) stotal = s;
    }
    __syncthreads();

    int c = stotal;
    bool overflow = (c > CAP) || (c < 0);
    if (overflow) c = 0;                 // main path skipped; fallback handles
    const int cpad = (c + 63) & ~63;

    // ---- gather survivors into contiguous LDS ----
    for (int idx = tid; idx < NANCH; idx += NMS_THREADS) {
        int ch = idx >> 6, k = idx & 63;
        if (k < scnt[ch] && !overflow)
            sv_[soff[ch] + k] = surv[((size_t)b * NCHUNK + ch) * 64 + k];
    }
    __syncthreads();

    // ---- rank-order sort: rank_i = #{j: key_j > key_i} (keys unique => exact) ----
    for (int i = tid; i < c; i += NMS_THREADS) {
        uint64_t ky = sv_[i].x;
        int r = 0;
        for (int j = 0; j < c; ++j) r += (sv_[j].x > ky) ? 1 : 0;
        sq[r] = sv_[i];
    }
    for (int i = c + tid; i < cpad; i += NMS_THREADS) sq[i] = make_ulonglong2(0ULL, 0ULL);
    __syncthreads();

    if (tid >= 64) return;

    // ---- wave 0: batched greedy NMS over sorted survivors ----
    int nk = 0;
    bool need_fb = overflow;
    bool done = false;

    for (int p0 = 0; p0 < cpad && !done; p0 += 64) {
        ulonglong2 kv = sq[p0 + lane];
        uint64_t key = kv.x, meta = kv.y;
        float s = key_score(key);                     // key==0 pad -> NaN -> invalid
        bool sval = (s > SCORE_TH);
        int cls_c = sval ? (int)(key & 0xFFFFu) : -1;
        float cx1 = (float)(short)(meta & 0xFFFFu);
        float cy1 = (float)(short)((meta >> 16) & 0xFFFFu);
        float cx2 = (float)(short)((meta >> 32) & 0xFFFFu);
        float cy2 = (float)(short)((meta >> 48) & 0xFFFFu);
        float ca = fmaxf(cx2 - cx1, 0.f) * fmaxf(cy2 - cy1, 0.f);

        sbox[lane]  = make_float4(cx1, cy1, cx2, cy2);
        sarea[lane] = ca;
        scls[lane]  = sval ? (int)(key & 0xFFFFu) : 0x7FFF;
        __builtin_amdgcn_wave_barrier();

        // vs previously-kept set (LDS broadcast reads)
        bool supk = false;
        for (int j = 0; j < nk; ++j) {
            float4 kb = kept_box[j];
            float ix1 = fmaxf(kb.x, cx1), iy1 = fmaxf(kb.y, cy1);
            float ix2 = fminf(kb.z, cx2), iy2 = fminf(kb.w, cy2);
            float inter = fmaxf(ix2 - ix1, 0.f) * fmaxf(iy2 - iy1, 0.f);
            supk |= (kept_cls[j] == cls_c) & (3.f * inter > kept_area[j] + ca);
        }
        bool alive0 = sval && !supk;

        // intra-batch pairwise suppression mask
        uint64_t supBy = 0;
#pragma unroll 4
        for (int t = 0; t < 64; ++t) {
            float4 tb = sbox[t];
            float ta = sarea[t];
            int tcls = scls[t];
            float ix1 = fmaxf(tb.x, cx1), iy1 = fmaxf(tb.y, cy1);
            float ix2 = fminf(tb.z, cx2), iy2 = fminf(tb.w, cy2);
            float inter = fmaxf(ix2 - ix1, 0.f) * fmaxf(iy2 - iy1, 0.f);
            bool sup = (t < lane) && (tcls == cls_c) && (3.f * inter > ta + ca);
            supBy |= ((uint64_t)sup) << t;
        }

        uint64_t aliveCand = __ballot(alive0);
        uint64_t aliveMask;
        if (__ballot(supBy != 0ULL) == 0ULL) {
            aliveMask = aliveCand;          // fast path: no intra-batch suppression
        } else {
            uint64_t killed = 0;
            for (int t = 0; t < 64; ++t) {
                uint64_t kill_t = __ballot((supBy >> t) & 1ULL);
                bool talive = ((aliveCand >> t) & 1ULL) && !((killed >> t) & 1ULL);
                if (talive) killed |= kill_t;
            }
            aliveMask = aliveCand & ~killed;
        }

        int myrank = __popcll(aliveMask & ((1ULL << lane) - 1ULL));
        bool keepme = ((aliveMask >> lane) & 1ULL) && (nk + myrank < MAXDET);
        if (keepme) {
            int slot = nk + myrank;
            kept_box[slot]  = make_float4(cx1, cy1, cx2, cy2);
            kept_area[slot] = ca;
            kept_cls[slot]  = cls_c;
            out[b * MAXDET + slot] = s;
            out[2 * MAXDET + b * MAXDET + slot] = (float)cls_c;
            float* ob = out + 4 * MAXDET + (size_t)(b * MAXDET + slot) * 4;
            ob[0] = cx1; ob[1] = cy1; ob[2] = cx2; ob[3] = cy2;
        }
        int navail = __popcll(aliveMask);
        int room = MAXDET - nk;
        nk += (navail < room) ? navail : room;

        uint64_t invalid = __ballot(!sval);
        if (nk >= MAXDET) done = true;
        else if (invalid) { need_fb = true; done = true; }   // survivors exhausted short
    }
    if (!done && nk < MAXDET) need_fb = true;

    // ---- cold exact fallback: repeated max-extraction over all 8192 keys ----
    if (need_fb) {
        const uint64_t* wkb = wk + (size_t)b * NANCH;
        const uint64_t* wmb = wm + (size_t)b * NANCH;
        for (int i = lane; i < NANCH / 64; i += 64) fbmap[i] = 0ULL;
        __builtin_amdgcn_wave_barrier();

        nk = 0;
        Kept K;
        K.cl[0] = K.cl[1] = -1;
        K.x1[0]=K.y1[0]=K.x2[0]=K.y2[0]=K.ar[0]=0.f;
        K.x1[1]=K.y1[1]=K.x2[1]=K.y2[1]=K.ar[1]=0.f;

        for (int iter = 0; iter < NANCH; ++iter) {
            uint64_t mybest = 0; int myq = -1;
            for (int q = lane; q < NANCH; q += 64) {
                bool cons = (fbmap[q >> 6] >> (q & 63)) & 1ULL;
                uint64_t kk = wkb[q];
                if (!cons && kk > mybest) { mybest = kk; myq = q; }
            }
            uint64_t best = mybest;
#pragma unroll
            for (int j = 32; j; j >>= 1) {
                uint64_t o = __shfl_xor(best, j);
                if (o > best) best = o;
            }
            if (best == 0ULL) break;
            float s = key_score(best);
            if (!(s > SCORE_TH)) break;
            uint64_t msk = __ballot(mybest == best);
            int wl = __ffsll((unsigned long long)msk) - 1;
            int q = __shfl(myq, wl);
            if (lane == wl) fbmap[q >> 6] |= (1ULL << (q & 63));
            uint64_t cm = wmb[q];
            nms_try_keep(best, cm, s, lane, nk, K, out, b);
            if (nk == MAXDET) break;
            __builtin_amdgcn_wave_barrier();
        }
    }

    // pad remaining slots with -1
    for (int t = nk + lane; t < MAXDET; t += 64) {
        out[b * MAXDET + t] = -1.f;
        out[2 * MAXDET + b * MAXDET + t] = -1.f;
        float* ob = out + 4 * MAXDET + (size_t)(b * MAXDET + t) * 4;
        ob[0] = -1.f; ob[1] = -1.f; ob[2] = -1.f; ob[3] = -1.f;
    }
}

extern "C" void kernel_launch(void* const* d_in, const int* in_sizes, int n_in,
                              void* d_out, int out_size, void* d_ws, size_t ws_size,
                              hipStream_t stream) {
    (void)in_sizes; (void)n_in; (void)out_size; (void)ws_size;
    const float* cls_heads = (const float*)d_in[0];
    const float* reg_heads = (const float*)d_in[1];
    const float* anchors   = (const float*)d_in[2];
    float* out = (float*)d_out;

    // ws layout (all offsets 256-aligned); every byte fully overwritten each call
    char* w = (char*)d_ws;
    int*        ccnt = (int*)w;                                  // 1 KiB (2*128 ints)
    uint64_t*   wk   = (uint64_t*)(w + 1024);                    // 128 KiB
    uint64_t*   wm   = (uint64_t*)(w + 1024 + 131072);           // 128 KiB
    ulonglong2* surv = (ulonglong2*)(w + 1024 + 262144);         // 256 KiB

    decode_kernel<<<dim3(NANCH / 256, 2), 256, 0, stream>>>(cls_heads, reg_heads, anchors,
                                                            ccnt, wk, wm, surv);
    sort_nms_kernel<<<dim3(2), NMS_THREADS, 0, stream>>>(ccnt, wk, wm, surv, out);
}

// Round 8
// 32.594 us; speedup vs baseline: 1.0124x; 1.0088x over previous
//
#include <hip/hip_runtime.h>
#include <stdint.h>

#define NANCH   8192
#define NCLS    80
#define NCHUNK  128            // 8192 / 64
#define IMW     1024
#define IMH     1024
#define MAXDET  100
#define KPAD    112            // kept arrays padded to multiple of 8 >= MAXDET+4
#define SCORE_TH 0.05f
#define TAU      0.9995f      // P(max80 > tau) ~= 0.0392 -> ~321 survivors/batch
#define CAP      1536         // LDS staging capacity (69 sigma above mean)
#define NMS_THREADS 512
#define KSENT    0x7FFFFFF0   // kept_cls sentinel: matches no candidate class

// key layout: [63:32] monotonic(score) | [31:16] ~anchor_idx (stable tie-break) | [15:0] class
// meta layout: 4 x int16 box coords (x1,y1,x2,y2)
__device__ __forceinline__ float key_score(uint64_t key) {
    uint32_t m = (uint32_t)(key >> 32);
    uint32_t bits = (m & 0x80000000u) ? (m & 0x7FFFFFFFu) : ~m;
    return __uint_as_float(bits);
}

// ---------------- Kernel 1: decode + per-chunk deterministic compaction ----------------
__global__ __launch_bounds__(256)
void decode_kernel(const float* __restrict__ cls_heads,
                   const float* __restrict__ reg_heads,
                   const float* __restrict__ anchors,
                   int* __restrict__ ccnt,
                   uint64_t* __restrict__ wk,
                   uint64_t* __restrict__ wm,
                   ulonglong2* __restrict__ surv) {
    const int tid  = threadIdx.x;
    const int lane = tid & 63;
    const int b    = blockIdx.y;
    const int n    = blockIdx.x * 256 + tid;
    const int chunk = n >> 6;
    const int row  = b * NANCH + n;

    const float4* cp = reinterpret_cast<const float4*>(cls_heads + (size_t)row * NCLS);
    float best = -1e30f; int bestj = 0;
#pragma unroll
    for (int k = 0; k < NCLS / 4; ++k) {
        float4 v = cp[k];
        if (v.x > best) { best = v.x; bestj = 4 * k + 0; }
        if (v.y > best) { best = v.y; bestj = 4 * k + 1; }
        if (v.z > best) { best = v.z; bestj = 4 * k + 2; }
        if (v.w > best) { best = v.w; bestj = 4 * k + 3; }
    }

    float4 r = reinterpret_cast<const float4*>(reg_heads)[row];
    float4 a = reinterpret_cast<const float4*>(anchors)[row];

    // decode — _rn intrinsics block fma contraction (trunc boundaries ulp-sensitive)
    float awx = __fsub_rn(a.z, a.x);
    float awy = __fsub_rn(a.w, a.y);
    float acx = __fadd_rn(a.x, __fmul_rn(0.5f, awx));
    float acy = __fadd_rn(a.y, __fmul_rn(0.5f, awy));
    float rx = __fmul_rn(r.x, 0.1f);
    float ry = __fmul_rn(r.y, 0.1f);
    float rw = __fmul_rn(r.z, 0.2f);
    float rh = __fmul_rn(r.w, 0.2f);
    float pwx = __fmul_rn(expf(rw), awx);
    float pwy = __fmul_rn(expf(rh), awy);
    float pcx = __fadd_rn(__fmul_rn(rx, awx), acx);
    float pcy = __fadd_rn(__fmul_rn(ry, awy), acy);

    int x1 = (int)__fsub_rn(pcx, __fmul_rn(0.5f, pwx));
    int y1 = (int)__fsub_rn(pcy, __fmul_rn(0.5f, pwy));
    int x2 = (int)__fadd_rn(pcx, __fmul_rn(0.5f, pwx));
    int y2 = (int)__fadd_rn(pcy, __fmul_rn(0.5f, pwy));
    x1 = max(x1, 0);
    y1 = max(y1, 0);
    x2 = min(x2, IMW - 1);
    y2 = min(y2, IMH - 1);

    uint32_t u = __float_as_uint(best);
    uint32_t mono = (u & 0x80000000u) ? ~u : (u | 0x80000000u);
    uint64_t key = ((uint64_t)mono << 32)
                 | ((uint64_t)((~(uint32_t)n) & 0xFFFFu) << 16)
                 | (uint64_t)(uint32_t)bestj;
    uint64_t meta = (uint64_t)(uint16_t)x1
                  | ((uint64_t)(uint16_t)y1 << 16)
                  | ((uint64_t)(uint16_t)x2 << 32)
                  | ((uint64_t)(uint16_t)y2 << 48);

    wk[row] = key;
    wm[row] = meta;

    // per-wave compaction into fixed per-chunk slots — no atomics, full overwrite each call
    bool svv = (best > TAU);
    uint64_t mask = __ballot(svv);
    int rank = __popcll(mask & ((1ULL << lane) - 1ULL));
    if (svv) surv[((size_t)b * NCHUNK + chunk) * 64 + rank] = make_ulonglong2(key, meta);
    if (lane == 0) ccnt[b * NCHUNK + chunk] = __popcll(mask);
}

// ---------------- fallback helper (cold path, exact) ----------------
struct Kept {
    float x1[2], y1[2], x2[2], y2[2], ar[2];
    int   cl[2];
};

__device__ __forceinline__ void nms_try_keep(uint64_t key, uint64_t meta, float s,
                                             int lane, int& nk, Kept& K,
                                             float* __restrict__ out, int b) {
    int cls = (int)(key & 0xFFFFu);
    float cx1 = (float)(short)(meta & 0xFFFFu);
    float cy1 = (float)(short)((meta >> 16) & 0xFFFFu);
    float cx2 = (float)(short)((meta >> 32) & 0xFFFFu);
    float cy2 = (float)(short)((meta >> 48) & 0xFFFFu);
    float ca = fmaxf(cx2 - cx1, 0.f) * fmaxf(cy2 - cy1, 0.f);

    bool supp = false;
#pragma unroll
    for (int r = 0; r < 2; ++r) {
        int slot = lane + 64 * r;
        if (slot < nk && K.cl[r] == cls) {
            float ix1 = fmaxf(K.x1[r], cx1), iy1 = fmaxf(K.y1[r], cy1);
            float ix2 = fminf(K.x2[r], cx2), iy2 = fminf(K.y2[r], cy2);
            float inter = fmaxf(ix2 - ix1, 0.f) * fmaxf(iy2 - iy1, 0.f);
            if (3.f * inter > K.ar[r] + ca) supp = true;   // exact iou>0.5 (ints exact in f32)
        }
    }
    if (__ballot(supp) != 0ULL) return;

    int rr = nk >> 6, l = nk & 63;
    if (lane == l) {
        if (rr == 0) { K.x1[0]=cx1; K.y1[0]=cy1; K.x2[0]=cx2; K.y2[0]=cy2; K.ar[0]=ca; K.cl[0]=cls; }
        else         { K.x1[1]=cx1; K.y1[1]=cy1; K.x2[1]=cx2; K.y2[1]=cy2; K.ar[1]=ca; K.cl[1]=cls; }
    }
    if (lane == 0) {
        out[b * MAXDET + nk] = s;
        out[2 * MAXDET + b * MAXDET + nk] = (float)cls;
        float* ob = out + 4 * MAXDET + (size_t)(b * MAXDET + nk) * 4;
        ob[0] = cx1; ob[1] = cy1; ob[2] = cx2; ob[3] = cy2;
    }
    ++nk;
}

// ---------------- Kernel 2: prefix-gather + rank sort + batched NMS ----------------
// All hot LDS loops are manually batched 8-wide: 8 independent ds_reads issue
// back-to-back before one lgkmcnt wait (G7 — latency hidden by ILP, not one
// dependent ds_read+wait per iteration).
__global__ __launch_bounds__(NMS_THREADS)
void sort_nms_kernel(const int* __restrict__ ccnt,
                     const uint64_t* __restrict__ wk,
                     const uint64_t* __restrict__ wm,
                     const ulonglong2* __restrict__ surv,
                     float* __restrict__ out) {
    __shared__ __align__(16) ulonglong2 sv_[CAP];    // gathered survivors (unordered)
    __shared__ __align__(16) ulonglong2 sq[CAP];     // rank-sorted survivors
    __shared__ __align__(16) uint64_t skey[CAP + 8]; // keys only (contiguous, pad-to-8)
    __shared__ int soff[NCHUNK];
    __shared__ int scnt[NCHUNK];
    __shared__ int stotal;
    __shared__ float4 kept_box[KPAD];
    __shared__ float  kept_area[KPAD];
    __shared__ int    kept_cls[KPAD];
    __shared__ float4 sbox[64];
    __shared__ float  sarea[64];
    __shared__ int    scls[64];
    __shared__ uint64_t fbmap[NANCH / 64];

    const int b = blockIdx.x;
    const int tid = threadIdx.x;
    const int lane = tid & 63;

    // kept sentinel init (matches no candidate class; pads the unrolled kept-loop)
    if (tid < KPAD) kept_cls[tid] = KSENT;

    // ---- wave 0: prefix-sum of the 128 per-chunk counts ----
    if (tid < 64) {
        int a0 = ccnt[b * NCHUNK + 2 * tid];
        int a1 = ccnt[b * NCHUNK + 2 * tid + 1];
        int s = a0 + a1;
#pragma unroll
        for (int j = 1; j < 64; j <<= 1) {
            int o = __shfl_up(s, j);
            if (lane >= j) s += o;
        }
        int excl = s - (a0 + a1);
        soff[2 * tid] = excl;
        soff[2 * tid + 1] = excl + a0;
        scnt[2 * tid] = a0;
        scnt[2 * tid + 1] = a1;
        if (tid == 63) stotal = s;
    }
    __syncthreads();

    int c = stotal;
    bool overflow = (c > CAP) || (c < 0);
    if (overflow) c = 0;                 // main path skipped; fallback handles
    const int cpad  = (c + 63) & ~63;
    const int cpad8 = (c + 7) & ~7;

    // ---- gather survivors into contiguous LDS (+ separate key array) ----
    for (int idx = tid; idx < NANCH; idx += NMS_THREADS) {
        int ch = idx >> 6, k = idx & 63;
        if (k < scnt[ch] && !overflow) {
            ulonglong2 v = surv[((size_t)b * NCHUNK + ch) * 64 + k];
            int pos = soff[ch] + k;
            sv_[pos]  = v;
            skey[pos] = v.x;
        }
    }
    for (int i = c + tid; i < cpad8; i += NMS_THREADS) skey[i] = 0ULL;   // rank pad
    __syncthreads();

    // ---- rank-order sort: rank_i = #{j: key_j > key_i} (keys unique => exact) ----
    for (int i = tid; i < c; i += NMS_THREADS) {
        uint64_t ky = skey[i];
        int r = 0;
        for (int j0 = 0; j0 < cpad8; j0 += 8) {
            int acc = 0;
#pragma unroll
            for (int u = 0; u < 8; ++u)
                acc += (skey[j0 + u] > ky) ? 1 : 0;    // 8 independent ds_reads per group
            r += acc;
        }
        sq[r] = sv_[i];
    }
    for (int i = c + tid; i < cpad; i += NMS_THREADS) sq[i] = make_ulonglong2(0ULL, 0ULL);
    __syncthreads();

    if (tid >= 64) return;

    // ---- wave 0: batched greedy NMS over sorted survivors ----
    int nk = 0;
    bool need_fb = overflow;
    bool done = false;

    for (int p0 = 0; p0 < cpad && !done; p0 += 64) {
        ulonglong2 kv = sq[p0 + lane];
        uint64_t key = kv.x, meta = kv.y;
        float s = key_score(key);                     // key==0 pad -> NaN -> invalid
        bool sval = (s > SCORE_TH);
        int cls_c = sval ? (int)(key & 0xFFFFu) : -1;
        float cx1 = (float)(short)(meta & 0xFFFFu);
        float cy1 = (float)(short)((meta >> 16) & 0xFFFFu);
        float cx2 = (float)(short)((meta >> 32) & 0xFFFFu);
        float cy2 = (float)(short)((meta >> 48) & 0xFFFFu);
        float ca = fmaxf(cx2 - cx1, 0.f) * fmaxf(cy2 - cy1, 0.f);

        sbox[lane]  = make_float4(cx1, cy1, cx2, cy2);
        sarea[lane] = ca;
        scls[lane]  = sval ? (int)(key & 0xFFFFu) : 0x7FFF;
        __builtin_amdgcn_wave_barrier();

        // vs previously-kept set — 8-wide batched LDS reads, sentinel-padded bound
        bool supk = false;
        int nkp = (nk + 7) & ~7;
        for (int j0 = 0; j0 < nkp; j0 += 8) {
#pragma unroll
            for (int u = 0; u < 8; ++u) {
                float4 kb = kept_box[j0 + u];
                float ka = kept_area[j0 + u];
                int kc = kept_cls[j0 + u];
                float ix1 = fmaxf(kb.x, cx1), iy1 = fmaxf(kb.y, cy1);
                float ix2 = fminf(kb.z, cx2), iy2 = fminf(kb.w, cy2);
                float inter = fmaxf(ix2 - ix1, 0.f) * fmaxf(iy2 - iy1, 0.f);
                supk |= (kc == cls_c) & (3.f * inter > ka + ca);
            }
        }
        bool alive0 = sval && !supk;

        // intra-batch pairwise suppression mask — 8-wide batched groups
        uint64_t supBy = 0;
        for (int t0 = 0; t0 < 64; t0 += 8) {
#pragma unroll
            for (int u = 0; u < 8; ++u) {
                int t = t0 + u;
                float4 tb = sbox[t];
                float ta = sarea[t];
                int tcls = scls[t];
                float ix1 = fmaxf(tb.x, cx1), iy1 = fmaxf(tb.y, cy1);
                float ix2 = fminf(tb.z, cx2), iy2 = fminf(tb.w, cy2);
                float inter = fmaxf(ix2 - ix1, 0.f) * fmaxf(iy2 - iy1, 0.f);
                bool sup = (t < lane) && (tcls == cls_c) && (3.f * inter > ta + ca);
                supBy |= ((uint64_t)sup) << t;
            }
        }

        uint64_t aliveCand = __ballot(alive0);
        uint64_t aliveMask;
        if (__ballot(supBy != 0ULL) == 0ULL) {
            aliveMask = aliveCand;          // fast path: no intra-batch suppression
        } else {
            uint64_t killed = 0;
            for (int t = 0; t < 64; ++t) {
                uint64_t kill_t = __ballot((supBy >> t) & 1ULL);
                bool talive = ((aliveCand >> t) & 1ULL) && !((killed >> t) & 1ULL);
                if (talive) killed |= kill_t;
            }
            aliveMask = aliveCand & ~killed;
        }

        int myrank = __popcll(aliveMask & ((1ULL << lane) - 1ULL));
        bool keepme = ((aliveMask >> lane) & 1ULL) && (nk + myrank < MAXDET);
        if (keepme) {
            int slot = nk + myrank;
            kept_box[slot]  = make_float4(cx1, cy1, cx2, cy2);
            kept_area[slot] = ca;
            kept_cls[slot]  = cls_c;
            out[b * MAXDET + slot] = s;
            out[2 * MAXDET + b * MAXDET + slot] = (float)cls_c;
            float* ob = out + 4 * MAXDET + (size_t)(b * MAXDET + slot) * 4;
            ob[0] = cx1; ob[1] = cy1; ob[2] = cx2; ob[3] = cy2;
        }
        int navail = __popcll(aliveMask);
        int room = MAXDET - nk;
        nk += (navail < room) ? navail : room;

        uint64_t invalid = __ballot(!sval);
        if (nk >= MAXDET) done = true;
        else if (invalid) { need_fb = true; done = true; }   // survivors exhausted short
    }
    if (!done && nk < MAXDET) need_fb = true;

    // ---- cold exact fallback: repeated max-extraction over all 8192 keys ----
    if (need_fb) {
        const uint64_t* wkb = wk + (size_t)b * NANCH;
        const uint64_t* wmb = wm + (size_t)b * NANCH;
        for (int i = lane; i < NANCH / 64; i += 64) fbmap[i] = 0ULL;
        __builtin_amdgcn_wave_barrier();

        nk = 0;
        Kept K;
        K.cl[0] = K.cl[1] = -1;
        K.x1[0]=K.y1[0]=K.x2[0]=K.y2[0]=K.ar[0]=0.f;
        K.x1[1]=K.y1[1]=K.x2[1]=K.y2[1]=K.ar[1]=0.f;

        for (int iter = 0; iter < NANCH; ++iter) {
            uint64_t mybest = 0; int myq = -1;
            for (int q = lane; q < NANCH; q += 64) {
                bool cons = (fbmap[q >> 6] >> (q & 63)) & 1ULL;
                uint64_t kk = wkb[q];
                if (!cons && kk > mybest) { mybest = kk; myq = q; }
            }
            uint64_t best = mybest;
#pragma unroll
            for (int j = 32; j; j >>= 1) {
                uint64_t o = __shfl_xor(best, j);
                if (o > best) best = o;
            }
            if (best == 0ULL) break;
            float s = key_score(best);
            if (!(s > SCORE_TH)) break;
            uint64_t msk = __ballot(mybest == best);
            int wl = __ffsll((unsigned long long)msk) - 1;
            int q = __shfl(myq, wl);
            if (lane == wl) fbmap[q >> 6] |= (1ULL << (q & 63));
            uint64_t cm = wmb[q];
            nms_try_keep(best, cm, s, lane, nk, K, out, b);
            if (nk == MAXDET) break;
            __builtin_amdgcn_wave_barrier();
        }
    }

    // pad remaining slots with -1
    for (int t = nk + lane; t < MAXDET; t += 64) {
        out[b * MAXDET + t] = -1.f;
        out[2 * MAXDET + b * MAXDET + t] = -1.f;
        float* ob = out + 4 * MAXDET + (size_t)(b * MAXDET + t) * 4;
        ob[0] = -1.f; ob[1] = -1.f; ob[2] = -1.f; ob[3] = -1.f;
    }
}

extern "C" void kernel_launch(void* const* d_in, const int* in_sizes, int n_in,
                              void* d_out, int out_size, void* d_ws, size_t ws_size,
                              hipStream_t stream) {
    (void)in_sizes; (void)n_in; (void)out_size; (void)ws_size;
    const float* cls_heads = (const float*)d_in[0];
    const float* reg_heads = (const float*)d_in[1];
    const float* anchors   = (const float*)d_in[2];
    float* out = (float*)d_out;

    // ws layout (all offsets 256-aligned); every byte fully overwritten each call
    char* w = (char*)d_ws;
    int*        ccnt = (int*)w;                                  // 1 KiB (2*128 ints)
    uint64_t*   wk   = (uint64_t*)(w + 1024);                    // 128 KiB
    uint64_t*   wm   = (uint64_t*)(w + 1024 + 131072);           // 128 KiB
    ulonglong2* surv = (ulonglong2*)(w + 1024 + 262144);         // 256 KiB

    decode_kernel<<<dim3(NANCH / 256, 2), 256, 0, stream>>>(cls_heads, reg_heads, anchors,
                                                            ccnt, wk, wm, surv);
    sort_nms_kernel<<<dim3(2), NMS_THREADS, 0, stream>>>(ccnt, wk, wm, surv, out);
}